// Round 1
// baseline (260.807 us; speedup 1.0000x reference)
//
#include <hip/hip_runtime.h>
#include <cmath>

// SSIM stability loss: 1 - mean(SSIM(x,y)), 11x11 Gaussian (sigma=1.5), zero SAME
// padding, fp32, 32 x 1 x 512 x 512.
//
// R14 config: 256 threads = 256 cols x row-band, H-rows streamed through an
// 11-row LDS chunk of v4f (x0,y0,x1,y1) units; 11-tap window read as 6 ALIGNED
// ds_read_b128, lane alignment parity folded into a 12-tap weight vector;
// packed v2f builtins; 11-deep circular register history for the vertical
// conv; software-pipelined window reads (w6cur/w6next); single dispatch,
// fp64 atomic finish.
//
// R14 -> R15: rocprof shows VALUBusy 45%, HBM 11%, Occupancy 15% -- pure
// latency bound. Grid (512 blocks = 2 blk/CU = 2 waves/SIMD) was the cap:
// VGPR(96) allows 5 waves/SIMD, LDS allows 6 blk/CU. Halve the band
// (BROWS 64 -> 32): grid 1024 = 4 blk/CU = 4 waves/SIMD, doubling TLP for
// +13.5% horizontal-halo work (42 H-rows per 32 outputs vs 74 per 64),
// +7.6% total VALU. Predict VALUBusy ~80%, dur ~30-36 us.

#define IMG   512
#define BROWS 32
#define NHROW (BROWS + 10)   // 42 H-rows per band
#define NCHUNK 4             // ceil(42/11)
#define CHR   11             // rows per LDS chunk (== history depth)
#define LCOLS 272            // staged cols per row (covers c0-8 .. c0+263)
#define LUNITS 68            // float4 units per staged row
#define NUNITS (CHR * LUNITS)   // 748
#define NBLOCKS 1024
#define NPIX  8388608.0

typedef float v2f __attribute__((ext_vector_type(2)));
typedef float v4f __attribute__((ext_vector_type(4)));

struct GaussW { float w[11]; };

__global__ __launch_bounds__(256, 4)
void ssim_stream_kernel(const float* __restrict__ x, const float* __restrict__ y,
                        double* __restrict__ acc_ws, unsigned long long* __restrict__ ctr,
                        float* __restrict__ out, GaussW gw) {
    // tile4[s][u] = LDS cols (2u, 2u+1) packed as (x0, y0, x1, y1); 16-B units
    __shared__ v4f tile4[CHR][LCOLS / 2];   // 11 * 136 * 16 = 23936 B
    __shared__ float wavesum[4];

    const int tid = threadIdx.x;
    const int c0 = blockIdx.x * 256;
    const int r0 = blockIdx.y * BROWS;
    const size_t img_off = (size_t)blockIdx.z * (IMG * IMG);
    const float* __restrict__ xb = x + img_off;
    const float* __restrict__ yb = y + img_off;

    const int ci = tid;                 // output column; taps at LDS cols ci+3..ci+13
    const int ub = (ci + 3) >> 1;       // v4f unit of aligned window base
    const int p  = (ci + 3) & 1;        // parity: tap k sits at window pos p+k

    // 12-tap per-lane weight vector: window pos m covers LDS col 2*ub + m;
    // logical tap k = m - p, so wv2[m] = w[m-p] (0 outside [0,10]).
    v2f wv2[12];
    #pragma unroll
    for (int m = 0; m < 12; ++m) {
        float lo = (m <= 10) ? gw.w[m] : 0.f;       // p == 0
        float hi = (m >= 1) ? gw.w[m - 1] : 0.f;    // p == 1
        float wm = p ? hi : lo;
        wv2[m][0] = wm; wv2[m][1] = wm;
    }
    v2f wp[11];                          // vertical weights (parity-free)
    #pragma unroll
    for (int k = 0; k < 11; ++k) { wp[k][0] = gw.w[k]; wp[k][1] = gw.w[k]; }

    float4 sxr[3], syr[3];   // staged regs for next chunk (3 iters x 256 thr >= 748)

    auto load_chunk = [&](int c) {
        #pragma unroll
        for (int it = 0; it < 3; ++it) {
            int idx = tid + it * 256;
            int row = idx / LUNITS;
            int u   = idx - row * LUNITS;
            int gr = r0 - 5 + c * CHR + row;       // global image row
            int gc = c0 - 8 + u * 4;               // global col of float4 (16B aligned)
            float4 vx = make_float4(0.f, 0.f, 0.f, 0.f);
            float4 vy = vx;
            if (idx < NUNITS && (unsigned)gr < IMG && (unsigned)gc < IMG) {
                const float* px = xb + (size_t)gr * IMG + gc;
                const float* py = yb + (size_t)gr * IMG + gc;
                vx = *(const float4*)px;
                vy = *(const float4*)py;
            }
            sxr[it] = vx; syr[it] = vy;
        }
    };
    auto store_chunk = [&]() {
        #pragma unroll
        for (int it = 0; it < 3; ++it) {
            int idx = tid + it * 256;
            if (idx < NUNITS) {
                int row = idx / LUNITS;
                int u   = idx - row * LUNITS;
                tile4[row][u * 2]     = (v4f){sxr[it].x, syr[it].x, sxr[it].y, syr[it].y};
                tile4[row][u * 2 + 1] = (v4f){sxr[it].z, syr[it].z, sxr[it].w, syr[it].w};
            }
        }
    };

    v2f hist01[11];    // (hx, hy)
    v2f hist23[11];    // (hxx, hyy)
    float hist4[11];   // hxy
    float lsum = 0.f;
    const float C1 = 1e-4f, C2 = 9e-4f;

    load_chunk(0);
    store_chunk();
    __syncthreads();

    #pragma unroll 1
    for (int c = 0; c < NCHUNK; ++c) {      // 4 chunks x 11 rows = 44 >= 42
        if (c < NCHUNK - 1) load_chunk(c + 1);  // global loads overlap chunk-c compute

        // software pipeline: window reads for row s+1 issued before computing
        // row s, so their ~150-cyc LDS latency hides under row s's VALU.
        v4f w6cur[6], w6next[6];
        #pragma unroll
        for (int i = 0; i < 6; ++i) w6cur[i] = tile4[0][ub + i];

        #pragma unroll
        for (int s = 0; s < CHR; ++s) {     // H-row m = 11c + s; hist slot = s
            if (!(c == NCHUNK - 1 && s >= NHROW - (NCHUNK - 1) * CHR)) {   // m < 42
                if (s < CHR - 1) {
                    #pragma unroll
                    for (int i = 0; i < 6; ++i) w6next[i] = tile4[s + 1][ub + i];
                }
                // --- horizontal conv: 12 taps from prefetched w6cur ---
                v2f h01 = (v2f){0.f, 0.f};
                v2f h23 = (v2f){0.f, 0.f};
                float h4 = 0.f;
                #pragma unroll
                for (int m = 0; m < 12; ++m) {
                    v2f t = (m & 1) ? w6cur[m >> 1].zw : w6cur[m >> 1].xy;
                    v2f tw = wv2[m] * t;                          // v_pk_mul_f32
                    h01 += tw;                                    // v_pk_add_f32
                    h23 = __builtin_elementwise_fma(tw, t, h23);  // v_pk_fma_f32
                    h4 = fmaf(tw[0], t[1], h4);                   // w*x*y (scalar)
                }
                hist01[s] = h01; hist23[s] = h23; hist4[s] = h4;

                // --- output row (11c + s - 10) completes now ---
                if (c > 0 || s == 10) {
                    v2f a01 = (v2f){0.f, 0.f};
                    v2f a23 = (v2f){0.f, 0.f};
                    float a4 = 0.f;
                    #pragma unroll
                    for (int j = 0; j < 11; ++j) {
                        const int sl = (s + 1 + j) % 11;   // static per (s,j)
                        a01 = __builtin_elementwise_fma(wp[j], hist01[sl], a01);
                        a23 = __builtin_elementwise_fma(wp[j], hist23[sl], a23);
                        a4 = fmaf(wp[j][0], hist4[sl], a4);
                    }
                    float mx = a01[0], my = a01[1];
                    float mxx = mx * mx, myy = my * my, mxy = mx * my;
                    float sxx = a23[0] - mxx, syy = a23[1] - myy, sxy = a4 - mxy;
                    float num = (2.f * mxy + C1) * (2.f * sxy + C2);
                    float den = (mxx + myy + C1) * (sxx + syy + C2);
                    lsum += num * __builtin_amdgcn_rcpf(den);
                }
                #pragma unroll
                for (int i = 0; i < 6; ++i) w6cur[i] = w6next[i];
            }
        }

        __syncthreads();                    // everyone done reading tile
        if (c < NCHUNK - 1) { store_chunk(); __syncthreads(); }
    }

    // ---- reduction: wave shuffle -> LDS -> block partial -> fp64 atomic ----
    #pragma unroll
    for (int off = 32; off > 0; off >>= 1)
        lsum += __shfl_down(lsum, off, 64);
    if ((tid & 63) == 0) wavesum[tid >> 6] = lsum;
    __syncthreads();
    if (tid == 0) {
        float bs = wavesum[0] + wavesum[1] + wavesum[2] + wavesum[3];
        atomicAdd(acc_ws, (double)bs);
        __threadfence();
        unsigned long long old = atomicAdd(ctr, 1ull);
        if (old == (unsigned long long)(NBLOCKS - 1)) {
            __threadfence();
            double total = atomicAdd(acc_ws, 0.0);   // atomic RMW sees all prior adds
            out[0] = (float)(1.0 - total / NPIX);
        }
    }
}

extern "C" void kernel_launch(void* const* d_in, const int* in_sizes, int n_in,
                              void* d_out, int out_size, void* d_ws, size_t ws_size,
                              hipStream_t stream) {
    const float* x = (const float*)d_in[0];   // heatmap_clean
    const float* y = (const float*)d_in[1];   // heatmap_adv
    float* out = (float*)d_out;
    double* acc = (double*)d_ws;
    unsigned long long* ctr = (unsigned long long*)((char*)d_ws + 8);

    // zero the 16B of accumulator+counter state (capture-safe async memset)
    hipMemsetAsync(d_ws, 0, 16, stream);

    GaussW gw;
    double g[11], s = 0.0;
    for (int i = 0; i < 11; ++i) { double d = i - 5; g[i] = exp(-(d * d) / 4.5); s += g[i]; }
    for (int i = 0; i < 11; ++i) gw.w[i] = (float)(g[i] / s);

    dim3 grid(2, IMG / BROWS, 32);   // (2, 16, 32) = 1024 blocks = 4 per CU
    ssim_stream_kernel<<<grid, 256, 0, stream>>>(x, y, acc, ctr, out, gw);
}

// Round 2
// 132.722 us; speedup vs baseline: 1.9651x; 1.9651x over previous
//
#include <hip/hip_runtime.h>
#include <cmath>

// SSIM stability loss: 1 - mean(SSIM(x,y)), 11x11 Gaussian (sigma=1.5), zero SAME
// padding, fp32, 32 x 1 x 512 x 512.
//
// Config: 256 threads = 256 cols x 32-row band, 42 H-rows streamed through an
// 11-row LDS chunk of v4f (x0,y0,x1,y1) units; 11-tap window read as 6 ALIGNED
// ds_read_b128, lane alignment parity folded into a 12-tap weight vector;
// packed v2f builtins; 11-deep circular register history for the vertical
// conv; software-pipelined window reads (w6cur/w6next); single dispatch,
// fp64 atomic finish.
//
// R15 post-mortem: __launch_bounds__(256,4) made the allocator target 64
// VGPR (8-wave budget) -> massive scratch spills (WRITE_SIZE 32KB->255MB,
// VALUBusy 14%, dur 188us). Occupancy DID rise 15->38%, validating the
// grid-doubling. R16: keep BROWS=32 / 1024 blocks, drop the min-waves hint.
// Plain __launch_bounds__(256) gave 96 VGPR on this structure; 96 <= 128 so
// HW allows 4 waves/SIMD anyway, and 4 x 24KB LDS fits. Predict: VGPR ~96,
// WRITE_SIZE back to ~32KB, VALUBusy ~75%, dur ~30-36us.

#define IMG   512
#define BROWS 32
#define NHROW (BROWS + 10)   // 42 H-rows per band
#define NCHUNK 4             // ceil(42/11)
#define CHR   11             // rows per LDS chunk (== history depth)
#define LCOLS 272            // staged cols per row (covers c0-8 .. c0+263)
#define LUNITS 68            // float4 units per staged row
#define NUNITS (CHR * LUNITS)   // 748
#define NBLOCKS 1024
#define NPIX  8388608.0

typedef float v2f __attribute__((ext_vector_type(2)));
typedef float v4f __attribute__((ext_vector_type(4)));

struct GaussW { float w[11]; };

__global__ __launch_bounds__(256)
void ssim_stream_kernel(const float* __restrict__ x, const float* __restrict__ y,
                        double* __restrict__ acc_ws, unsigned long long* __restrict__ ctr,
                        float* __restrict__ out, GaussW gw) {
    // tile4[s][u] = LDS cols (2u, 2u+1) packed as (x0, y0, x1, y1); 16-B units
    __shared__ v4f tile4[CHR][LCOLS / 2];   // 11 * 136 * 16 = 23936 B
    __shared__ float wavesum[4];

    const int tid = threadIdx.x;
    const int c0 = blockIdx.x * 256;
    const int r0 = blockIdx.y * BROWS;
    const size_t img_off = (size_t)blockIdx.z * (IMG * IMG);
    const float* __restrict__ xb = x + img_off;
    const float* __restrict__ yb = y + img_off;

    const int ci = tid;                 // output column; taps at LDS cols ci+3..ci+13
    const int ub = (ci + 3) >> 1;       // v4f unit of aligned window base
    const int p  = (ci + 3) & 1;        // parity: tap k sits at window pos p+k

    // 12-tap per-lane weight vector: window pos m covers LDS col 2*ub + m;
    // logical tap k = m - p, so wv2[m] = w[m-p] (0 outside [0,10]).
    v2f wv2[12];
    #pragma unroll
    for (int m = 0; m < 12; ++m) {
        float lo = (m <= 10) ? gw.w[m] : 0.f;       // p == 0
        float hi = (m >= 1) ? gw.w[m - 1] : 0.f;    // p == 1
        float wm = p ? hi : lo;
        wv2[m][0] = wm; wv2[m][1] = wm;
    }
    v2f wp[11];                          // vertical weights (parity-free)
    #pragma unroll
    for (int k = 0; k < 11; ++k) { wp[k][0] = gw.w[k]; wp[k][1] = gw.w[k]; }

    float4 sxr[3], syr[3];   // staged regs for next chunk (3 iters x 256 thr >= 748)

    auto load_chunk = [&](int c) {
        #pragma unroll
        for (int it = 0; it < 3; ++it) {
            int idx = tid + it * 256;
            int row = idx / LUNITS;
            int u   = idx - row * LUNITS;
            int gr = r0 - 5 + c * CHR + row;       // global image row
            int gc = c0 - 8 + u * 4;               // global col of float4 (16B aligned)
            float4 vx = make_float4(0.f, 0.f, 0.f, 0.f);
            float4 vy = vx;
            if (idx < NUNITS && (unsigned)gr < IMG && (unsigned)gc < IMG) {
                const float* px = xb + (size_t)gr * IMG + gc;
                const float* py = yb + (size_t)gr * IMG + gc;
                vx = *(const float4*)px;
                vy = *(const float4*)py;
            }
            sxr[it] = vx; syr[it] = vy;
        }
    };
    auto store_chunk = [&]() {
        #pragma unroll
        for (int it = 0; it < 3; ++it) {
            int idx = tid + it * 256;
            if (idx < NUNITS) {
                int row = idx / LUNITS;
                int u   = idx - row * LUNITS;
                tile4[row][u * 2]     = (v4f){sxr[it].x, syr[it].x, sxr[it].y, syr[it].y};
                tile4[row][u * 2 + 1] = (v4f){sxr[it].z, syr[it].z, sxr[it].w, syr[it].w};
            }
        }
    };

    v2f hist01[11];    // (hx, hy)
    v2f hist23[11];    // (hxx, hyy)
    float hist4[11];   // hxy
    float lsum = 0.f;
    const float C1 = 1e-4f, C2 = 9e-4f;

    load_chunk(0);
    store_chunk();
    __syncthreads();

    #pragma unroll 1
    for (int c = 0; c < NCHUNK; ++c) {      // 4 chunks x 11 rows = 44 >= 42
        if (c < NCHUNK - 1) load_chunk(c + 1);  // global loads overlap chunk-c compute

        // software pipeline: window reads for row s+1 issued before computing
        // row s, so their ~150-cyc LDS latency hides under row s's VALU.
        v4f w6cur[6], w6next[6];
        #pragma unroll
        for (int i = 0; i < 6; ++i) w6cur[i] = tile4[0][ub + i];

        #pragma unroll
        for (int s = 0; s < CHR; ++s) {     // H-row m = 11c + s; hist slot = s
            if (!(c == NCHUNK - 1 && s >= NHROW - (NCHUNK - 1) * CHR)) {   // m < 42
                if (s < CHR - 1) {
                    #pragma unroll
                    for (int i = 0; i < 6; ++i) w6next[i] = tile4[s + 1][ub + i];
                }
                // --- horizontal conv: 12 taps from prefetched w6cur ---
                v2f h01 = (v2f){0.f, 0.f};
                v2f h23 = (v2f){0.f, 0.f};
                float h4 = 0.f;
                #pragma unroll
                for (int m = 0; m < 12; ++m) {
                    v2f t = (m & 1) ? w6cur[m >> 1].zw : w6cur[m >> 1].xy;
                    v2f tw = wv2[m] * t;                          // v_pk_mul_f32
                    h01 += tw;                                    // v_pk_add_f32
                    h23 = __builtin_elementwise_fma(tw, t, h23);  // v_pk_fma_f32
                    h4 = fmaf(tw[0], t[1], h4);                   // w*x*y (scalar)
                }
                hist01[s] = h01; hist23[s] = h23; hist4[s] = h4;

                // --- output row (11c + s - 10) completes now ---
                if (c > 0 || s == 10) {
                    v2f a01 = (v2f){0.f, 0.f};
                    v2f a23 = (v2f){0.f, 0.f};
                    float a4 = 0.f;
                    #pragma unroll
                    for (int j = 0; j < 11; ++j) {
                        const int sl = (s + 1 + j) % 11;   // static per (s,j)
                        a01 = __builtin_elementwise_fma(wp[j], hist01[sl], a01);
                        a23 = __builtin_elementwise_fma(wp[j], hist23[sl], a23);
                        a4 = fmaf(wp[j][0], hist4[sl], a4);
                    }
                    float mx = a01[0], my = a01[1];
                    float mxx = mx * mx, myy = my * my, mxy = mx * my;
                    float sxx = a23[0] - mxx, syy = a23[1] - myy, sxy = a4 - mxy;
                    float num = (2.f * mxy + C1) * (2.f * sxy + C2);
                    float den = (mxx + myy + C1) * (sxx + syy + C2);
                    lsum += num * __builtin_amdgcn_rcpf(den);
                }
                #pragma unroll
                for (int i = 0; i < 6; ++i) w6cur[i] = w6next[i];
            }
        }

        __syncthreads();                    // everyone done reading tile
        if (c < NCHUNK - 1) { store_chunk(); __syncthreads(); }
    }

    // ---- reduction: wave shuffle -> LDS -> block partial -> fp64 atomic ----
    #pragma unroll
    for (int off = 32; off > 0; off >>= 1)
        lsum += __shfl_down(lsum, off, 64);
    if ((tid & 63) == 0) wavesum[tid >> 6] = lsum;
    __syncthreads();
    if (tid == 0) {
        float bs = wavesum[0] + wavesum[1] + wavesum[2] + wavesum[3];
        atomicAdd(acc_ws, (double)bs);
        __threadfence();
        unsigned long long old = atomicAdd(ctr, 1ull);
        if (old == (unsigned long long)(NBLOCKS - 1)) {
            __threadfence();
            double total = atomicAdd(acc_ws, 0.0);   // atomic RMW sees all prior adds
            out[0] = (float)(1.0 - total / NPIX);
        }
    }
}

extern "C" void kernel_launch(void* const* d_in, const int* in_sizes, int n_in,
                              void* d_out, int out_size, void* d_ws, size_t ws_size,
                              hipStream_t stream) {
    const float* x = (const float*)d_in[0];   // heatmap_clean
    const float* y = (const float*)d_in[1];   // heatmap_adv
    float* out = (float*)d_out;
    double* acc = (double*)d_ws;
    unsigned long long* ctr = (unsigned long long*)((char*)d_ws + 8);

    // zero the 16B of accumulator+counter state (capture-safe async memset)
    hipMemsetAsync(d_ws, 0, 16, stream);

    GaussW gw;
    double g[11], s = 0.0;
    for (int i = 0; i < 11; ++i) { double d = i - 5; g[i] = exp(-(d * d) / 4.5); s += g[i]; }
    for (int i = 0; i < 11; ++i) gw.w[i] = (float)(g[i] / s);

    dim3 grid(2, IMG / BROWS, 32);   // (2, 16, 32) = 1024 blocks = 4 per CU
    ssim_stream_kernel<<<grid, 256, 0, stream>>>(x, y, acc, ctr, out, gw);
}

// Round 3
// 124.260 us; speedup vs baseline: 2.0989x; 1.0681x over previous
//
#include <hip/hip_runtime.h>
#include <cmath>

// SSIM stability loss: 1 - mean(SSIM(x,y)), 11x11 Gaussian (sigma=1.5), zero SAME
// padding, fp32, 32 x 1 x 512 x 512.
//
// Config: 256 threads = 256 cols x 64-row band, 74 H-rows streamed through an
// 11-row LDS chunk of v4f (x0,y0,x1,y1) units; 11-tap window read as 6 ALIGNED
// ds_read_b128, lane alignment parity folded into a 12-tap weight vector;
// packed v2f builtins; 11-deep circular register history for the vertical
// conv; single dispatch, fp64 atomic finish. 512 blocks = 2/CU.
//
// R16 post-mortem: grid-doubling (BROWS=32) did NOT raise measured occupancy
// (15% at both 512 and 1024 blocks); VALU-busy-time scaled exactly with the
// +7.6% halo work. Occupancy lever refuted -> revert to BROWS=64.
// R17: waves stall ~78% of life on LDS latency. R14's w6cur/w6next pipeline
// cost 24 v_mov/row (+13% instrs, R11 47us -> R14 51us) and the compiler
// sank the reads anyway. Replace with a 2-row modulo schedule: disjoint
// register sets wA/wB, unroll rows by 2: {read wB(s+1); compute(s,wA);
// read wA(s+2); compute(s+1,wB)} -- zero copies, reads issued a full row
// (~100 VALU instrs) ahead, compiler emits counted lgkmcnt(6).
// Predict: dur 62 -> 40-45us, VALUBusy ~52-62%, VGPR ~96-110, no spills.

#define IMG   512
#define BROWS 64
#define NHROW (BROWS + 10)   // 74 H-rows per band
#define NCHUNK 7             // ceil(74/11)
#define CHR   11             // rows per LDS chunk (== history depth)
#define LCOLS 272            // staged cols per row (covers c0-8 .. c0+263)
#define LUNITS 68            // float4 units per staged row
#define NUNITS (CHR * LUNITS)   // 748
#define NBLOCKS 512
#define NPIX  8388608.0

typedef float v2f __attribute__((ext_vector_type(2)));
typedef float v4f __attribute__((ext_vector_type(4)));

struct GaussW { float w[11]; };

__global__ __launch_bounds__(256)
void ssim_stream_kernel(const float* __restrict__ x, const float* __restrict__ y,
                        double* __restrict__ acc_ws, unsigned long long* __restrict__ ctr,
                        float* __restrict__ out, GaussW gw) {
    // tile4[s][u] = LDS cols (2u, 2u+1) packed as (x0, y0, x1, y1); 16-B units
    __shared__ v4f tile4[CHR][LCOLS / 2];   // 11 * 136 * 16 = 23936 B
    __shared__ float wavesum[4];

    const int tid = threadIdx.x;
    const int c0 = blockIdx.x * 256;
    const int r0 = blockIdx.y * BROWS;
    const size_t img_off = (size_t)blockIdx.z * (IMG * IMG);
    const float* __restrict__ xb = x + img_off;
    const float* __restrict__ yb = y + img_off;

    const int ci = tid;                 // output column; taps at LDS cols ci+3..ci+13
    const int ub = (ci + 3) >> 1;       // v4f unit of aligned window base
    const int p  = (ci + 3) & 1;        // parity: tap k sits at window pos p+k

    // 12-tap per-lane weight vector: window pos m covers LDS col 2*ub + m;
    // logical tap k = m - p, so wv2[m] = w[m-p] (0 outside [0,10]).
    v2f wv2[12];
    #pragma unroll
    for (int m = 0; m < 12; ++m) {
        float lo = (m <= 10) ? gw.w[m] : 0.f;       // p == 0
        float hi = (m >= 1) ? gw.w[m - 1] : 0.f;    // p == 1
        float wm = p ? hi : lo;
        wv2[m][0] = wm; wv2[m][1] = wm;
    }
    v2f wp[11];                          // vertical weights (parity-free)
    #pragma unroll
    for (int k = 0; k < 11; ++k) { wp[k][0] = gw.w[k]; wp[k][1] = gw.w[k]; }

    float4 sxr[3], syr[3];   // staged regs for next chunk (3 iters x 256 thr >= 748)

    auto load_chunk = [&](int c) {
        #pragma unroll
        for (int it = 0; it < 3; ++it) {
            int idx = tid + it * 256;
            int row = idx / LUNITS;
            int u   = idx - row * LUNITS;
            int gr = r0 - 5 + c * CHR + row;       // global image row
            int gc = c0 - 8 + u * 4;               // global col of float4 (16B aligned)
            float4 vx = make_float4(0.f, 0.f, 0.f, 0.f);
            float4 vy = vx;
            if (idx < NUNITS && (unsigned)gr < IMG && (unsigned)gc < IMG) {
                const float* px = xb + (size_t)gr * IMG + gc;
                const float* py = yb + (size_t)gr * IMG + gc;
                vx = *(const float4*)px;
                vy = *(const float4*)py;
            }
            sxr[it] = vx; syr[it] = vy;
        }
    };
    auto store_chunk = [&]() {
        #pragma unroll
        for (int it = 0; it < 3; ++it) {
            int idx = tid + it * 256;
            if (idx < NUNITS) {
                int row = idx / LUNITS;
                int u   = idx - row * LUNITS;
                tile4[row][u * 2]     = (v4f){sxr[it].x, syr[it].x, sxr[it].y, syr[it].y};
                tile4[row][u * 2 + 1] = (v4f){sxr[it].z, syr[it].z, sxr[it].w, syr[it].w};
            }
        }
    };

    v2f hist01[11];    // (hx, hy)
    v2f hist23[11];    // (hxx, hyy)
    float hist4[11];   // hxy
    float lsum = 0.f;
    const float C1 = 1e-4f, C2 = 9e-4f;

    load_chunk(0);
    store_chunk();
    __syncthreads();

    #pragma unroll 1
    for (int c = 0; c < NCHUNK; ++c) {      // 7 chunks x 11 rows = 77 >= 74
        if (c < NCHUNK - 1) load_chunk(c + 1);  // global loads overlap chunk-c compute

        // compute one H-row from a prefetched 6-unit window register set
        auto compute_row = [&](int s, const v4f (&w6)[6]) {
            // --- horizontal conv: 12 taps ---
            v2f h01 = (v2f){0.f, 0.f};
            v2f h23 = (v2f){0.f, 0.f};
            float h4 = 0.f;
            #pragma unroll
            for (int m = 0; m < 12; ++m) {
                v2f t = (m & 1) ? w6[m >> 1].zw : w6[m >> 1].xy;
                v2f tw = wv2[m] * t;                          // v_pk_mul_f32
                h01 += tw;                                    // v_pk_add_f32
                h23 = __builtin_elementwise_fma(tw, t, h23);  // v_pk_fma_f32
                h4 = fmaf(tw[0], t[1], h4);                   // w*x*y (scalar)
            }
            hist01[s] = h01; hist23[s] = h23; hist4[s] = h4;

            // --- output row (11c + s - 10) completes now ---
            if (c > 0 || s == 10) {
                v2f a01 = (v2f){0.f, 0.f};
                v2f a23 = (v2f){0.f, 0.f};
                float a4 = 0.f;
                #pragma unroll
                for (int j = 0; j < 11; ++j) {
                    const int sl = (s + 1 + j) % 11;   // static per (s,j)
                    a01 = __builtin_elementwise_fma(wp[j], hist01[sl], a01);
                    a23 = __builtin_elementwise_fma(wp[j], hist23[sl], a23);
                    a4 = fmaf(wp[j][0], hist4[sl], a4);
                }
                float mx = a01[0], my = a01[1];
                float mxx = mx * mx, myy = my * my, mxy = mx * my;
                float sxx = a23[0] - mxx, syy = a23[1] - myy, sxy = a4 - mxy;
                float num = (2.f * mxy + C1) * (2.f * sxy + C2);
                float den = (mxx + myy + C1) * (sxx + syy + C2);
                lsum += num * __builtin_amdgcn_rcpf(den);
            }
        };

        // 2-row modulo schedule: disjoint wA/wB, reads issued one row ahead,
        // no register copies.
        v4f wA[6], wB[6];
        #pragma unroll
        for (int i = 0; i < 6; ++i) wA[i] = tile4[0][ub + i];

        const int base = c * CHR;
        #pragma unroll
        for (int s = 0; s < CHR; s += 2) {   // s = 0,2,4,6,8,10
            if (base + s < NHROW) {          // wave-uniform guard (last chunk: 8 rows)
                if (s + 1 < CHR) {
                    #pragma unroll
                    for (int i = 0; i < 6; ++i) wB[i] = tile4[s + 1][ub + i];
                }
                compute_row(s, wA);
            }
            if (s + 1 < CHR && base + s + 1 < NHROW) {
                if (s + 2 < CHR) {
                    #pragma unroll
                    for (int i = 0; i < 6; ++i) wA[i] = tile4[s + 2][ub + i];
                }
                compute_row(s + 1, wB);
            }
        }

        __syncthreads();                    // everyone done reading tile
        if (c < NCHUNK - 1) { store_chunk(); __syncthreads(); }
    }

    // ---- reduction: wave shuffle -> LDS -> block partial -> fp64 atomic ----
    #pragma unroll
    for (int off = 32; off > 0; off >>= 1)
        lsum += __shfl_down(lsum, off, 64);
    if ((tid & 63) == 0) wavesum[tid >> 6] = lsum;
    __syncthreads();
    if (tid == 0) {
        float bs = wavesum[0] + wavesum[1] + wavesum[2] + wavesum[3];
        atomicAdd(acc_ws, (double)bs);
        __threadfence();
        unsigned long long old = atomicAdd(ctr, 1ull);
        if (old == (unsigned long long)(NBLOCKS - 1)) {
            __threadfence();
            double total = atomicAdd(acc_ws, 0.0);   // atomic RMW sees all prior adds
            out[0] = (float)(1.0 - total / NPIX);
        }
    }
}

extern "C" void kernel_launch(void* const* d_in, const int* in_sizes, int n_in,
                              void* d_out, int out_size, void* d_ws, size_t ws_size,
                              hipStream_t stream) {
    const float* x = (const float*)d_in[0];   // heatmap_clean
    const float* y = (const float*)d_in[1];   // heatmap_adv
    float* out = (float*)d_out;
    double* acc = (double*)d_ws;
    unsigned long long* ctr = (unsigned long long*)((char*)d_ws + 8);

    // zero the 16B of accumulator+counter state (capture-safe async memset)
    hipMemsetAsync(d_ws, 0, 16, stream);

    GaussW gw;
    double g[11], s = 0.0;
    for (int i = 0; i < 11; ++i) { double d = i - 5; g[i] = exp(-(d * d) / 4.5); s += g[i]; }
    for (int i = 0; i < 11; ++i) gw.w[i] = (float)(g[i] / s);

    dim3 grid(2, IMG / BROWS, 32);   // (2, 8, 32) = 512 blocks = 2 per CU
    ssim_stream_kernel<<<grid, 256, 0, stream>>>(x, y, acc, ctr, out, gw);
}